// Round 17
// baseline (139.426 us; speedup 1.0000x reference)
//
#include <hip/hip_runtime.h>
#include <hip/hip_bf16.h>

typedef float f32x4 __attribute__((ext_vector_type(4)));
typedef __bf16 bf16x8 __attribute__((ext_vector_type(8)));
typedef unsigned short u16x8 __attribute__((ext_vector_type(8)));
typedef unsigned short u16x4 __attribute__((ext_vector_type(4)));
typedef int i32x4 __attribute__((ext_vector_type(4)));

#define NEG_BIG_F (-1000000000.0f)
#define SCALE_F 0.044194173824159216f

__device__ __forceinline__ unsigned short f2bf(float f) {
  unsigned int u = __float_as_uint(f);
  u += 0x7FFFu + ((u >> 16) & 1u);   // round-to-nearest-even
  return (unsigned short)(u >> 16);
}

__device__ __forceinline__ float bf2f(unsigned short h) {
  return __uint_as_float((unsigned int)h << 16);
}

__device__ __forceinline__ u16x8 cvt8(f32x4 a, f32x4 b) {
  u16x8 r;
  r[0] = f2bf(a[0]); r[1] = f2bf(a[1]); r[2] = f2bf(a[2]); r[3] = f2bf(a[3]);
  r[4] = f2bf(b[0]); r[5] = f2bf(b[1]); r[6] = f2bf(b[2]); r[7] = f2bf(b[3]);
  return r;
}

__device__ __forceinline__ bf16x8 u2b(u16x8 u) {
  union { u16x8 u; bf16x8 b; } c; c.u = u; return c.b;
}

__device__ __forceinline__ void gload16(const void* g, char* l) {
  __builtin_amdgcn_global_load_lds(
      (const __attribute__((address_space(1))) unsigned int*)g,
      (__attribute__((address_space(3))) unsigned int*)l, 16, 0, 0);
}

// ---------------------------------------------------------------------------
// cvtW: three 512x512 fp32 weight matrices -> bf16 (weights ONLY, ~6 MB).
// Q, K, V are consumed as fp32 directly by proj_all.
// ---------------------------------------------------------------------------
__global__ __launch_bounds__(256) void cvtW(
    const float* __restrict__ w0, const float* __restrict__ w1,
    const float* __restrict__ w2, unsigned short* __restrict__ wb)
{
  const int i = (blockIdx.x * 256 + threadIdx.x) * 8;   // grid 384 -> 786432
  const float* src = i < 262144 ? w0 : (i < 524288 ? w1 : w2);
  const int j = i & 262143;
  f32x4 a = *(const f32x4*)(src + j);
  f32x4 b = *(const f32x4*)(src + j + 4);
  *(u16x8*)&wb[i] = cvt8(a, b);
}

// ---------------------------------------------------------------------------
// proj_all (768 blocks, 80 KB LDS pool -> 2 blocks/CU):
//   blocks 0-511: qk-role (R10 projqk verbatim, proven) — 128x256 tile,
//     A = fp32 Q/K via gload into swizzled f32 LDS (slot^(row&7)), cvt bf16
//     at fragment read; B = bf16 W (slot^((row>>1)&3)). vmcnt(4). 64 KB.
//   blocks 512-767: v-role (R16 verbatim) — 128(e)x256(s), A = wv bf16
//     gload, B = V fp32 gload into swizzled f32 tile + cvt. vmcnt(5). 80 KB.
// ---------------------------------------------------------------------------
__global__ __launch_bounds__(512, 2) void proj_all(
    const float* __restrict__ Q, const float* __restrict__ Kx,
    const float* __restrict__ V, const unsigned short* __restrict__ wb,
    unsigned short* __restrict__ qb, unsigned short* __restrict__ kb,
    unsigned short* __restrict__ vt)
{
  __shared__ __align__(16) char pool[81920];   // 80 KB

  const int bid = blockIdx.x;
  const int tid = threadIdx.x;
  const int lane = tid & 63, wave = tid >> 6;
  const int fr = lane & 15, fq = lane >> 4;

  if (bid < 512) {
    // ------------- qk-role (R10 projqk body, f32 A) -------------
    float          (*Af)[128][32] = (float (*)[128][32])pool;            // 32 KB
    unsigned short (*Bs)[256][32] = (unsigned short (*)[256][32])(pool + 32768);  // 32 KB

    const int z = bid >> 8, rem = bid & 255;
    const float* X = z ? Kx : Q;
    const unsigned short* W = wb + (size_t)z * 262144;
    unsigned short* Y = z ? kb : qb;
    const int m0 = (rem >> 1) * 128, n0 = (rem & 1) * 256;
    const int wr = (wave >> 2) * 64, wc = (wave & 3) * 64;

    f32x4 acc[4][4] = {};

    const float* gA[2]; char* lA[2];
    #pragma unroll
    for (int i = 0; i < 2; i++) {
      const int c = tid + 512 * i, row = c >> 3, slot = c & 7;
      gA[i] = X + (size_t)(m0 + row) * 512 + (slot ^ (row & 7)) * 4;
      lA[i] = pool + c * 16;
    }
    const unsigned short* gB[2]; char* lB[2];
    #pragma unroll
    for (int i = 0; i < 2; i++) {
      const int c = tid + 512 * i, row = c >> 2, slot = c & 3;
      gB[i] = W + (size_t)(n0 + row) * 512 + (slot ^ ((row >> 1) & 3)) * 8;
      lB[i] = pool + 32768 + c * 16;
    }

    #pragma unroll
    for (int i = 0; i < 2; i++) { gload16(gA[i], lA[i]); gload16(gB[i], lB[i]); }

    int cur = 0;
    for (int kt = 0; kt < 512; kt += 32) {
      const int nb = cur ^ 1;
      if (kt < 480) {
        #pragma unroll
        for (int i = 0; i < 2; i++) {
          gload16(gA[i] + kt + 32, lA[i] + nb * 16384);
          gload16(gB[i] + kt + 32, lB[i] + nb * 16384);
        }
        asm volatile("s_waitcnt vmcnt(4) lgkmcnt(0)" ::: "memory");
      } else {
        asm volatile("s_waitcnt vmcnt(0) lgkmcnt(0)" ::: "memory");
      }
      __builtin_amdgcn_sched_barrier(0);
      __builtin_amdgcn_s_barrier();

      bf16x8 av[4], bv[4];
      #pragma unroll
      for (int nf = 0; nf < 4; nf++) {
        const int br = wc + nf * 16 + fr;
        bv[nf] = *(const bf16x8*)&Bs[cur][br][(fq ^ ((br >> 1) & 3)) * 8];
      }
      #pragma unroll
      for (int mf = 0; mf < 4; mf++) {
        const int ar = wr + mf * 16 + fr;
        f32x4 lo = *(const f32x4*)&Af[cur][ar][((fq * 2)     ^ (ar & 7)) * 4];
        f32x4 hi = *(const f32x4*)&Af[cur][ar][((fq * 2 + 1) ^ (ar & 7)) * 4];
        av[mf] = u2b(cvt8(lo, hi));
      }
      #pragma unroll
      for (int mf = 0; mf < 4; mf++)
        #pragma unroll
        for (int nf = 0; nf < 4; nf++)
          acc[mf][nf] = __builtin_amdgcn_mfma_f32_16x16x32_bf16(av[mf], bv[nf], acc[mf][nf], 0, 0, 0);
      __builtin_amdgcn_s_barrier();
      cur = nb;
    }

    #pragma unroll
    for (int mf = 0; mf < 4; mf++)
      #pragma unroll
      for (int nf = 0; nf < 4; nf++)
        #pragma unroll
        for (int rr = 0; rr < 4; rr++) {
          const int m = m0 + wr + mf * 16 + fq * 4 + rr;
          const int n = n0 + wc + nf * 16 + fr;
          Y[(size_t)m * 512 + n] = f2bf(acc[mf][nf][rr]);
        }
  } else {
    // ------------- v-role (R16 verbatim, f32 B) -------------
    unsigned short (*As)[128][32] = (unsigned short (*)[128][32])pool;   // 16 KB
    float          (*Bf)[256][32] = (float (*)[256][32])(pool + 16384);  // 64 KB

    const int bid2 = bid - 512;
    const int m0 = (bid2 & 3) * 128, n0 = ((bid2 >> 2) & 3) * 256, b = bid2 >> 4;
    const int wr = (wave >> 2) * 64, wc = (wave & 3) * 64;
    const unsigned short* wv = wb + 524288;

    f32x4 acc[4][4] = {};

    const int arw = tid >> 2, asl = tid & 3;
    const unsigned short* gA = wv + (size_t)(m0 + arw) * 512 + (asl ^ ((arw >> 1) & 3)) * 8;
    char* lA = pool + tid * 16;
    const float* gB[4]; char* lB[4];
    #pragma unroll
    for (int i = 0; i < 4; i++) {
      const int c = tid + 512 * i, row = c >> 3, slot = c & 7;
      gB[i] = V + ((size_t)b * 1024 + n0 + row) * 512 + (slot ^ (row & 7)) * 4;
      lB[i] = pool + 16384 + c * 16;
    }

    gload16(gA, lA);
    #pragma unroll
    for (int i = 0; i < 4; i++) gload16(gB[i], lB[i]);

    int cur = 0;
    for (int kt = 0; kt < 512; kt += 32) {
      const int nb = cur ^ 1;
      if (kt < 480) {
        gload16(gA + kt + 32, lA + nb * 8192);
        #pragma unroll
        for (int i = 0; i < 4; i++) gload16(gB[i] + kt + 32, lB[i] + nb * 32768);
        asm volatile("s_waitcnt vmcnt(5) lgkmcnt(0)" ::: "memory");
      } else {
        asm volatile("s_waitcnt vmcnt(0) lgkmcnt(0)" ::: "memory");
      }
      __builtin_amdgcn_sched_barrier(0);
      __builtin_amdgcn_s_barrier();

      bf16x8 av[4], bv[4];
      #pragma unroll
      for (int mf = 0; mf < 4; mf++) {
        const int ar = wr + mf * 16 + fr;
        av[mf] = *(const bf16x8*)&As[cur][ar][(fq ^ ((ar >> 1) & 3)) * 8];
      }
      #pragma unroll
      for (int nf = 0; nf < 4; nf++) {
        const int br = wc + nf * 16 + fr;
        f32x4 lo = *(const f32x4*)&Bf[cur][br][((fq * 2)     ^ (br & 7)) * 4];
        f32x4 hi = *(const f32x4*)&Bf[cur][br][((fq * 2 + 1) ^ (br & 7)) * 4];
        bv[nf] = u2b(cvt8(lo, hi));
      }
      #pragma unroll
      for (int mf = 0; mf < 4; mf++)
        #pragma unroll
        for (int nf = 0; nf < 4; nf++)
          acc[mf][nf] = __builtin_amdgcn_mfma_f32_16x16x32_bf16(av[mf], bv[nf], acc[mf][nf], 0, 0, 0);
      __builtin_amdgcn_s_barrier();
      cur = nb;
    }

    #pragma unroll
    for (int mf = 0; mf < 4; mf++)
      #pragma unroll
      for (int nf = 0; nf < 4; nf++)
        #pragma unroll
        for (int rr = 0; rr < 4; rr++) {
          const int e = m0 + wr + mf * 16 + fq * 4 + rr;
          const int s = n0 + wc + nf * 16 + fr;
          vt[((size_t)b * 512 + e) * 1024 + s] = f2bf(acc[mf][nf][rr]);
        }
  }
}

// ---------------------------------------------------------------------------
// score_mv: blocks 0-255 = scores->P''+partials (XCD-swizzled);
// 256-1279 = mvsum. (R16 verbatim — proven)
// ---------------------------------------------------------------------------
__global__ __launch_bounds__(512, 2) void score_mv(
    const unsigned short* __restrict__ qb, const unsigned short* __restrict__ kb,
    const unsigned short* __restrict__ vt, const int* __restrict__ mask,
    unsigned short* __restrict__ P, float* __restrict__ partial,
    float* __restrict__ mvsum)
{
  __shared__ __align__(16) unsigned short As[2][256][32];
  __shared__ __align__(16) unsigned short Bs[2][256][32];

  const int bid = blockIdx.x;
  const int tid = threadIdx.x;

  if (bid >= 256) {
    const int row = (bid - 256) * 8 + (tid >> 6);
    const int b = row >> 9;
    const int lane = tid & 63;
    const unsigned short* vr = vt + (size_t)row * 1024 + lane * 16;
    const int* mr = mask + b * 1024 + lane * 16;
    u16x8 v0 = *(const u16x8*)(vr);
    u16x8 v1 = *(const u16x8*)(vr + 8);
    float s = 0.f;
    #pragma unroll
    for (int j = 0; j < 8; j++) {
      if (!mr[j])     s += bf2f(v0[j]);
      if (!mr[8 + j]) s += bf2f(v1[j]);
    }
    #pragma unroll
    for (int o = 32; o > 0; o >>= 1) s += __shfl_xor(s, o);
    if (lane == 0) mvsum[row] = s;
    return;
  }

  const int xcd = bid & 7, idx = bid >> 3;
  const int bz = xcd * 2 + (idx >> 4);
  const int tile = idx & 15;
  const int m0 = (tile & 3) * 256, n0 = ((tile >> 2) & 3) * 256;
  const int lane = tid & 63, wave = tid >> 6;
  const int wr = (wave >> 2) * 128, wc = (wave & 3) * 64;
  const int fr = lane & 15, fq = lane >> 4;

  f32x4 acc[8][4] = {};

  const unsigned short* gA[2]; char* lA[2];
  const unsigned short* gB[2]; char* lB[2];
  #pragma unroll
  for (int i = 0; i < 2; i++) {
    const int c = tid + 512 * i, row = c >> 2, slot = c & 3;
    const int sw = (slot ^ ((row >> 1) & 3)) * 8;
    gA[i] = qb + ((size_t)bz * 1024 + m0 + row) * 512 + sw;
    gB[i] = kb + ((size_t)bz * 1024 + n0 + row) * 512 + sw;
    lA[i] = (char*)&As[0][0][0] + c * 16;
    lB[i] = (char*)&Bs[0][0][0] + c * 16;
  }

  #pragma unroll
  for (int i = 0; i < 2; i++) { gload16(gA[i], lA[i]); gload16(gB[i], lB[i]); }

  int cur = 0;
  for (int kt = 0; kt < 512; kt += 32) {
    const int nb = cur ^ 1;
    if (kt < 480) {
      #pragma unroll
      for (int i = 0; i < 2; i++) {
        gload16(gA[i] + kt + 32, lA[i] + nb * 16384);
        gload16(gB[i] + kt + 32, lB[i] + nb * 16384);
      }
      asm volatile("s_waitcnt vmcnt(4) lgkmcnt(0)" ::: "memory");
    } else {
      asm volatile("s_waitcnt vmcnt(0) lgkmcnt(0)" ::: "memory");
    }
    __builtin_amdgcn_sched_barrier(0);
    __builtin_amdgcn_s_barrier();

    bf16x8 bv[4];
    #pragma unroll
    for (int nf = 0; nf < 4; nf++) {
      const int br = wc + nf * 16 + fr;
      bv[nf] = *(const bf16x8*)&Bs[cur][br][(fq ^ ((br >> 1) & 3)) * 8];
    }
    #pragma unroll
    for (int mf = 0; mf < 8; mf++) {
      const int ar = wr + mf * 16 + fr;
      bf16x8 av = *(const bf16x8*)&As[cur][ar][(fq ^ ((ar >> 1) & 3)) * 8];
      #pragma unroll
      for (int nf = 0; nf < 4; nf++)
        acc[mf][nf] = __builtin_amdgcn_mfma_f32_16x16x32_bf16(av, bv[nf], acc[mf][nf], 0, 0, 0);
    }
    __builtin_amdgcn_s_barrier();
    cur = nb;
  }

  int mcol[4];
  #pragma unroll
  for (int nf = 0; nf < 4; nf++)
    mcol[nf] = mask[bz * 1024 + n0 + wc + nf * 16 + fr];

  unsigned short* Pb = P + ((size_t)bz << 20);
  const int slot = ((tile >> 2) & 3) * 4 + (wave & 3);
  #pragma unroll
  for (int mf = 0; mf < 8; mf++) {
    #pragma unroll
    for (int rr = 0; rr < 4; rr++) {
      const int m = m0 + wr + mf * 16 + fq * 4 + rr;
      float e = 0.f;
      #pragma unroll
      for (int nf = 0; nf < 4; nf++) {
        const float ev = __expf(acc[mf][nf][rr] * SCALE_F);
        e += ev;
        Pb[(size_t)m * 1024 + n0 + wc + nf * 16 + fr] =
            mcol[nf] ? f2bf(ev) : (unsigned short)0;
      }
      e += __shfl_xor(e, 1); e += __shfl_xor(e, 2);
      e += __shfl_xor(e, 4); e += __shfl_xor(e, 8);
      if (fr == 0)
        partial[(size_t)slot * 16384 + bz * 1024 + m] = e;
    }
  }
}

// ---------------------------------------------------------------------------
// pv_attn: XCD-swizzled bf16 GEMM out = inv*(P''·vt^T) - 1e9*mvsum, with the
// final attn write fused into the K-loop. (R16 verbatim — proven)
// ---------------------------------------------------------------------------
__global__ __launch_bounds__(512) void pv_attn(
    const unsigned short* __restrict__ P, const unsigned short* __restrict__ vt,
    const float* __restrict__ partial, const float* __restrict__ mvsum,
    const int* __restrict__ mask,
    float* __restrict__ out, float* __restrict__ attn)
{
  __shared__ __align__(16) unsigned short As[2][64][32];   // 8 KB
  __shared__ __align__(16) unsigned short Bs[2][512][32];  // 64 KB
  __shared__ float inv_l[64];

  const int tid = threadIdx.x;
  const int lin = blockIdx.x;
  const int xcd = lin & 7, idx = lin >> 3;
  const int bz = xcd * 2 + (idx >> 4);
  const int m0 = (idx & 15) * 64;
  const int lane = tid & 63, wave = tid >> 6;
  const int n0 = wave * 64;
  const int fr = lane & 15, fq = lane >> 4;

  f32x4 acc[4][4] = {};

  if (tid < 64) {
    float s = 0.f;
    #pragma unroll
    for (int p = 0; p < 16; p++) s += partial[(size_t)p * 16384 + bz * 1024 + m0 + tid];
    inv_l[tid] = 1.0f / s;
  }

  const unsigned short* gA = nullptr; char* lA = nullptr;
  if (tid < 256) {
    const int row = tid >> 2, slot = tid & 3;
    gA = P + ((size_t)bz << 20) + (size_t)(m0 + row) * 1024 + (slot ^ ((row >> 1) & 3)) * 8;
    lA = (char*)&As[0][0][0] + tid * 16;
  }
  const unsigned short* gB[4]; char* lB[4];
  #pragma unroll
  for (int i = 0; i < 4; i++) {
    const int c = tid + 512 * i, row = c >> 2, slot = c & 3;
    gB[i] = vt + ((size_t)bz * 512 + row) * 1024 + (slot ^ ((row >> 1) & 3)) * 8;
    lB[i] = (char*)&Bs[0][0][0] + c * 16;
  }

  const int arow = tid >> 3, acol = (tid & 7) * 4;
  const int aslot8 = ((acol >> 3) ^ ((arow >> 1) & 3)) * 8 + (acol & 7);
  float* arp = attn + ((size_t)bz * 1024 + m0 + arow) * 1024 + acol;
  const int* mrp = mask + bz * 1024 + acol;

  if (tid < 256) gload16(gA, lA);
  #pragma unroll
  for (int i = 0; i < 4; i++) gload16(gB[i], lB[i]);
  __syncthreads();

  int cur = 0;
  for (int t = 0; t < 32; t++) {
    const int nb = cur ^ 1;
    const int kt = t * 32;
    if (t < 31) {
      if (tid < 256) gload16(gA + kt + 32, lA + nb * 4096);
      #pragma unroll
      for (int i = 0; i < 4; i++) gload16(gB[i] + kt + 32, lB[i] + nb * 32768);
      if (wave < 4) asm volatile("s_waitcnt vmcnt(5) lgkmcnt(0)" ::: "memory");
      else          asm volatile("s_waitcnt vmcnt(4) lgkmcnt(0)" ::: "memory");
    } else {
      asm volatile("s_waitcnt vmcnt(0) lgkmcnt(0)" ::: "memory");
    }
    __builtin_amdgcn_sched_barrier(0);
    __builtin_amdgcn_s_barrier();

    bf16x8 af[4], bv[4];
    #pragma unroll
    for (int mf = 0; mf < 4; mf++) {
      const int ar = mf * 16 + fr;
      af[mf] = *(const bf16x8*)&As[cur][ar][(fq ^ ((ar >> 1) & 3)) * 8];
    }
    #pragma unroll
    for (int nf = 0; nf < 4; nf++) {
      const int br = n0 + nf * 16 + fr;
      bv[nf] = *(const bf16x8*)&Bs[cur][br][(fq ^ ((br >> 1) & 3)) * 8];
    }
    #pragma unroll
    for (int mf = 0; mf < 4; mf++)
      #pragma unroll
      for (int nf = 0; nf < 4; nf++)
        acc[mf][nf] = __builtin_amdgcn_mfma_f32_16x16x32_bf16(af[mf], bv[nf], acc[mf][nf], 0, 0, 0);

    {
      const u16x4 pv4 = *(const u16x4*)&As[cur][arow][aslot8];
      const i32x4 mv = *(const i32x4*)(mrp + kt);
      const float iv = inv_l[arow];
      f32x4 o;
      o[0] = mv[0] ? bf2f(pv4[0]) * iv : NEG_BIG_F;
      o[1] = mv[1] ? bf2f(pv4[1]) * iv : NEG_BIG_F;
      o[2] = mv[2] ? bf2f(pv4[2]) * iv : NEG_BIG_F;
      o[3] = mv[3] ? bf2f(pv4[3]) * iv : NEG_BIG_F;
      *(f32x4*)(arp + kt) = o;
    }
    __builtin_amdgcn_s_barrier();
    cur = nb;
  }

  float mvv[4];
  #pragma unroll
  for (int nf = 0; nf < 4; nf++)
    mvv[nf] = mvsum[bz * 512 + n0 + nf * 16 + fr];
  #pragma unroll
  for (int mf = 0; mf < 4; mf++)
    #pragma unroll
    for (int rr = 0; rr < 4; rr++) {
      const int m = m0 + mf * 16 + fq * 4 + rr;
      const float iv = inv_l[mf * 16 + fq * 4 + rr];
      #pragma unroll
      for (int nf = 0; nf < 4; nf++)
        out[((size_t)bz * 1024 + m) * 512 + n0 + nf * 16 + fr] =
            iv * acc[mf][nf][rr] + NEG_BIG_F * mvv[nf];
    }
}

// ---------------------------------------------------------------------------
extern "C" void kernel_launch(void* const* d_in, const int* in_sizes, int n_in,
                              void* d_out, int out_size, void* d_ws, size_t ws_size,
                              hipStream_t stream)
{
  const float* Q  = (const float*)d_in[0];
  const float* Kx = (const float*)d_in[1];
  const float* V  = (const float*)d_in[2];
  const float* WQ = (const float*)d_in[3];
  const float* WK = (const float*)d_in[4];
  const float* WV = (const float*)d_in[5];
  const int* mask = (const int*)d_in[6];

  const int B = 16, S = 1024, D = 512;
  float* out_f  = (float*)d_out;                      // B*S*D fp32 (final out)
  float* attn_f = out_f + (size_t)B * S * D;          // B*S*S fp32 (final attn)
  unsigned short* Pbuf = (unsigned short*)d_out;      // P'' aliases out region

  // ws: qb | kb | vt (8.39M ushorts each) | wb (0.79M) | partial | mvsum
  unsigned short* qb = (unsigned short*)d_ws;
  unsigned short* kb = qb + (size_t)B * S * D;
  unsigned short* vt = kb + (size_t)B * S * D;
  unsigned short* wb = vt + (size_t)B * S * D;
  float* partial = (float*)(wb + 786432);             // 16 x 16384 f32
  float* mvsum = partial + 262144;                    // 16 x 512 f32

  cvtW<<<dim3(384), 256, 0, stream>>>(WQ, WK, WV, wb);
  proj_all<<<dim3(768), 512, 0, stream>>>(Q, Kx, V, wb, qb, kb, vt);
  score_mv<<<dim3(1280), 512, 0, stream>>>(qb, kb, vt, mask, Pbuf, partial, mvsum);
  pv_attn<<<dim3(256), 512, 0, stream>>>(Pbuf, vt, partial, mvsum, mask, out_f, attn_f);
}

// Round 18
// 136.629 us; speedup vs baseline: 1.0205x; 1.0205x over previous
//
#include <hip/hip_runtime.h>
#include <hip/hip_bf16.h>

typedef float f32x4 __attribute__((ext_vector_type(4)));
typedef __bf16 bf16x8 __attribute__((ext_vector_type(8)));
typedef unsigned short u16x8 __attribute__((ext_vector_type(8)));
typedef unsigned short u16x4 __attribute__((ext_vector_type(4)));
typedef int i32x4 __attribute__((ext_vector_type(4)));

#define NEG_BIG_F (-1000000000.0f)
#define SCALE_F 0.044194173824159216f

__device__ __forceinline__ unsigned short f2bf(float f) {
  unsigned int u = __float_as_uint(f);
  u += 0x7FFFu + ((u >> 16) & 1u);   // round-to-nearest-even
  return (unsigned short)(u >> 16);
}

__device__ __forceinline__ float bf2f(unsigned short h) {
  return __uint_as_float((unsigned int)h << 16);
}

__device__ __forceinline__ u16x8 cvt8(f32x4 a, f32x4 b) {
  u16x8 r;
  r[0] = f2bf(a[0]); r[1] = f2bf(a[1]); r[2] = f2bf(a[2]); r[3] = f2bf(a[3]);
  r[4] = f2bf(b[0]); r[5] = f2bf(b[1]); r[6] = f2bf(b[2]); r[7] = f2bf(b[3]);
  return r;
}

__device__ __forceinline__ bf16x8 u2b(u16x8 u) {
  union { u16x8 u; bf16x8 b; } c; c.u = u; return c.b;
}

__device__ __forceinline__ void gload16(const void* g, char* l) {
  __builtin_amdgcn_global_load_lds(
      (const __attribute__((address_space(1))) unsigned int*)g,
      (__attribute__((address_space(3))) unsigned int*)l, 16, 0, 0);
}

// ---------------------------------------------------------------------------
// cvtWX: convert W (z=0) and Q/K (z=1,2) fp32 -> bf16. V stays fp32 and is
// consumed directly by proj_all's v-role. (R16 verbatim)
// ---------------------------------------------------------------------------
__global__ __launch_bounds__(256) void cvtWX(
    const float* __restrict__ w0, const float* __restrict__ w1,
    const float* __restrict__ w2, const float* __restrict__ Q,
    const float* __restrict__ Kx,
    unsigned short* __restrict__ wb, unsigned short* __restrict__ xb)
{
  const int z = blockIdx.z;
  if (z == 0) {
    if (blockIdx.x >= 384) return;
    const int i = (blockIdx.x * 256 + threadIdx.x) * 8;
    const float* src = i < 262144 ? w0 : (i < 524288 ? w1 : w2);
    const int j = i & 262143;
    f32x4 a = *(const f32x4*)(src + j);
    f32x4 b = *(const f32x4*)(src + j + 4);
    *(u16x8*)&wb[i] = cvt8(a, b);
  } else {
    const float* src = z == 1 ? Q : Kx;
    unsigned short* dst = xb + (size_t)(z - 1) * 8388608;
    const int i = (blockIdx.x * 256 + threadIdx.x) * 8;
    f32x4 a = *(const f32x4*)(src + i);
    f32x4 b = *(const f32x4*)(src + i + 4);
    *(u16x8*)&dst[i] = cvt8(a, b);
  }
}

// ---------------------------------------------------------------------------
// proj_all (R16 verbatim — best measured): 512 blocks, 80 KB pool.
//   0-255: qk-role — 256x256 all-bf16 GEMM (gload both sides, vmcnt(4)).
//   256-511: v-role — 128(e)x256(s); A = wv bf16 gload, B = V fp32 gload
//     into swizzled f32 tile + cvt at read, vmcnt(5).
// ---------------------------------------------------------------------------
__global__ __launch_bounds__(512, 2) void proj_all(
    const unsigned short* __restrict__ xb, const float* __restrict__ V,
    const unsigned short* __restrict__ wb,
    unsigned short* __restrict__ qb, unsigned short* __restrict__ kb,
    unsigned short* __restrict__ vt)
{
  __shared__ __align__(16) char pool[81920];   // 80 KB

  const int bid = blockIdx.x;
  const int tid = threadIdx.x;
  const int lane = tid & 63, wave = tid >> 6;
  const int fr = lane & 15, fq = lane >> 4;

  if (bid < 256) {
    unsigned short (*As)[256][32] = (unsigned short (*)[256][32])pool;
    unsigned short (*Bs)[256][32] = (unsigned short (*)[256][32])(pool + 32768);

    const int z = bid >> 7, rem = bid & 127;
    const int m0 = (rem & 63) * 256, n0 = (rem >> 6) * 256;
    const unsigned short* Abase = xb + (size_t)z * 8388608 + (size_t)m0 * 512;
    const unsigned short* Bbase = wb + (size_t)z * 262144 + (size_t)n0 * 512;
    const int wr = (wave >> 2) * 128, wc = (wave & 3) * 64;

    f32x4 acc[8][4] = {};

    const unsigned short* gA[2]; char* lA[2];
    const unsigned short* gB[2]; char* lB[2];
    #pragma unroll
    for (int i = 0; i < 2; i++) {
      const int c = tid + 512 * i, row = c >> 2, slot = c & 3;
      const int sw = (slot ^ ((row >> 1) & 3)) * 8;
      gA[i] = Abase + (size_t)row * 512 + sw;
      gB[i] = Bbase + (size_t)row * 512 + sw;
      lA[i] = pool + c * 16;
      lB[i] = pool + 32768 + c * 16;
    }

    #pragma unroll
    for (int i = 0; i < 2; i++) { gload16(gA[i], lA[i]); gload16(gB[i], lB[i]); }

    int cur = 0;
    for (int kt = 0; kt < 512; kt += 32) {
      const int nb = cur ^ 1;
      if (kt < 480) {
        #pragma unroll
        for (int i = 0; i < 2; i++) {
          gload16(gA[i] + kt + 32, lA[i] + nb * 16384);
          gload16(gB[i] + kt + 32, lB[i] + nb * 16384);
        }
        asm volatile("s_waitcnt vmcnt(4) lgkmcnt(0)" ::: "memory");
      } else {
        asm volatile("s_waitcnt vmcnt(0) lgkmcnt(0)" ::: "memory");
      }
      __builtin_amdgcn_sched_barrier(0);
      __builtin_amdgcn_s_barrier();

      bf16x8 bv[4];
      #pragma unroll
      for (int nf = 0; nf < 4; nf++) {
        const int br = wc + nf * 16 + fr;
        bv[nf] = *(const bf16x8*)&Bs[cur][br][(fq ^ ((br >> 1) & 3)) * 8];
      }
      #pragma unroll
      for (int mf = 0; mf < 8; mf++) {
        const int ar = wr + mf * 16 + fr;
        bf16x8 av = *(const bf16x8*)&As[cur][ar][(fq ^ ((ar >> 1) & 3)) * 8];
        #pragma unroll
        for (int nf = 0; nf < 4; nf++)
          acc[mf][nf] = __builtin_amdgcn_mfma_f32_16x16x32_bf16(av, bv[nf], acc[mf][nf], 0, 0, 0);
      }
      __builtin_amdgcn_s_barrier();
      cur = nb;
    }

    unsigned short* Y = z ? kb : qb;
    #pragma unroll
    for (int mf = 0; mf < 8; mf++)
      #pragma unroll
      for (int nf = 0; nf < 4; nf++)
        #pragma unroll
        for (int rr = 0; rr < 4; rr++) {
          const int m = m0 + wr + mf * 16 + fq * 4 + rr;
          const int n = n0 + wc + nf * 16 + fr;
          Y[(size_t)m * 512 + n] = f2bf(acc[mf][nf][rr]);
        }
  } else {
    unsigned short (*As)[128][32] = (unsigned short (*)[128][32])pool;
    float          (*Bf)[256][32] = (float (*)[256][32])(pool + 16384);

    const int bid2 = bid - 256;
    const int m0 = (bid2 & 3) * 128, n0 = ((bid2 >> 2) & 3) * 256, b = bid2 >> 4;
    const int wr = (wave >> 2) * 64, wc = (wave & 3) * 64;
    const unsigned short* wv = wb + 524288;

    f32x4 acc[4][4] = {};

    const int arw = tid >> 2, asl = tid & 3;
    const unsigned short* gA = wv + (size_t)(m0 + arw) * 512 + (asl ^ ((arw >> 1) & 3)) * 8;
    char* lA = pool + tid * 16;
    const float* gB[4]; char* lB[4];
    #pragma unroll
    for (int i = 0; i < 4; i++) {
      const int c = tid + 512 * i, row = c >> 3, slot = c & 7;
      gB[i] = V + ((size_t)b * 1024 + n0 + row) * 512 + (slot ^ (row & 7)) * 4;
      lB[i] = pool + 16384 + c * 16;
    }

    gload16(gA, lA);
    #pragma unroll
    for (int i = 0; i < 4; i++) gload16(gB[i], lB[i]);

    int cur = 0;
    for (int kt = 0; kt < 512; kt += 32) {
      const int nb = cur ^ 1;
      if (kt < 480) {
        gload16(gA + kt + 32, lA + nb * 8192);
        #pragma unroll
        for (int i = 0; i < 4; i++) gload16(gB[i] + kt + 32, lB[i] + nb * 32768);
        asm volatile("s_waitcnt vmcnt(5) lgkmcnt(0)" ::: "memory");
      } else {
        asm volatile("s_waitcnt vmcnt(0) lgkmcnt(0)" ::: "memory");
      }
      __builtin_amdgcn_sched_barrier(0);
      __builtin_amdgcn_s_barrier();

      bf16x8 av[4], bv[4];
      #pragma unroll
      for (int mf = 0; mf < 4; mf++) {
        const int ar = wr + mf * 16 + fr;
        av[mf] = *(const bf16x8*)&As[cur][ar][(fq ^ ((ar >> 1) & 3)) * 8];
      }
      #pragma unroll
      for (int nf = 0; nf < 4; nf++) {
        const int br = wc + nf * 16 + fr;
        f32x4 lo = *(const f32x4*)&Bf[cur][br][((fq * 2)     ^ (br & 7)) * 4];
        f32x4 hi = *(const f32x4*)&Bf[cur][br][((fq * 2 + 1) ^ (br & 7)) * 4];
        bv[nf] = u2b(cvt8(lo, hi));
      }
      #pragma unroll
      for (int mf = 0; mf < 4; mf++)
        #pragma unroll
        for (int nf = 0; nf < 4; nf++)
          acc[mf][nf] = __builtin_amdgcn_mfma_f32_16x16x32_bf16(av[mf], bv[nf], acc[mf][nf], 0, 0, 0);
      __builtin_amdgcn_s_barrier();
      cur = nb;
    }

    #pragma unroll
    for (int mf = 0; mf < 4; mf++)
      #pragma unroll
      for (int nf = 0; nf < 4; nf++)
        #pragma unroll
        for (int rr = 0; rr < 4; rr++) {
          const int e = m0 + wr + mf * 16 + fq * 4 + rr;
          const int s = n0 + wc + nf * 16 + fr;
          vt[((size_t)b * 512 + e) * 1024 + s] = f2bf(acc[mf][nf][rr]);
        }
  }
}

// ---------------------------------------------------------------------------
// score_mv (R18): score role retiled 256x128 (A 32KB + B 16KB = 48 KB ->
// 3 blocks/CU capacity, grid 512 = 2 blocks/CU for cross-block drain
// hiding, m114). Waves 4Mx2N (wave tile 64x64, 16 MFMA/iter), vmcnt(3).
// XCD swizzle: 64 blocks = 2 complete batches per XCD. Blocks 512-1535 =
// mvsum (8 rows/block).
// ---------------------------------------------------------------------------
__global__ __launch_bounds__(512, 2) void score_mv(
    const unsigned short* __restrict__ qb, const unsigned short* __restrict__ kb,
    const unsigned short* __restrict__ vt, const int* __restrict__ mask,
    unsigned short* __restrict__ P, float* __restrict__ partial,
    float* __restrict__ mvsum)
{
  __shared__ __align__(16) unsigned short As[2][256][32];  // 32 KB
  __shared__ __align__(16) unsigned short Bs[2][128][32];  // 16 KB

  const int bid = blockIdx.x;
  const int tid = threadIdx.x;

  if (bid >= 512) {
    const int row = (bid - 512) * 8 + (tid >> 6);   // 0..8191 = b*512+e
    const int b = row >> 9;
    const int lane = tid & 63;
    const unsigned short* vr = vt + (size_t)row * 1024 + lane * 16;
    const int* mr = mask + b * 1024 + lane * 16;
    u16x8 v0 = *(const u16x8*)(vr);
    u16x8 v1 = *(const u16x8*)(vr + 8);
    float s = 0.f;
    #pragma unroll
    for (int j = 0; j < 8; j++) {
      if (!mr[j])     s += bf2f(v0[j]);
      if (!mr[8 + j]) s += bf2f(v1[j]);
    }
    #pragma unroll
    for (int o = 32; o > 0; o >>= 1) s += __shfl_xor(s, o);
    if (lane == 0) mvsum[row] = s;
    return;
  }

  // XCD-aware decode: xcd = bid&7; each XCD owns 2 complete batches
  // (32 tiles/batch: 4 m-tiles x 8 n-tiles).
  const int xcd = bid & 7, idx = bid >> 3;        // idx 0..63
  const int bz = xcd * 2 + (idx >> 5);
  const int tile = idx & 31;
  const int m0 = (tile & 3) * 256;
  const int ntile = tile >> 2;                    // 0..7
  const int n0 = ntile * 128;
  const int lane = tid & 63, wave = tid >> 6;
  const int wr = (wave >> 1) * 64, wc = (wave & 1) * 64;
  const int fr = lane & 15, fq = lane >> 4;

  f32x4 acc[4][4] = {};

  // A: 1024 chunks, 2/thread (rows 0..255). B: 512 chunks, 1/thread (rows 0..127).
  const unsigned short* gA[2]; char* lA[2];
  #pragma unroll
  for (int i = 0; i < 2; i++) {
    const int c = tid + 512 * i, row = c >> 2, slot = c & 3;
    gA[i] = qb + ((size_t)bz * 1024 + m0 + row) * 512 + (slot ^ ((row >> 1) & 3)) * 8;
    lA[i] = (char*)&As[0][0][0] + c * 16;
  }
  const int brw = tid >> 2, bsl = tid & 3;
  const unsigned short* gB = kb + ((size_t)bz * 1024 + n0 + brw) * 512 + (bsl ^ ((brw >> 1) & 3)) * 8;
  char* lB = (char*)&Bs[0][0][0] + tid * 16;

  #pragma unroll
  for (int i = 0; i < 2; i++) gload16(gA[i], lA[i]);
  gload16(gB, lB);

  int cur = 0;
  for (int kt = 0; kt < 512; kt += 32) {
    const int nb = cur ^ 1;
    if (kt < 480) {
      #pragma unroll
      for (int i = 0; i < 2; i++) gload16(gA[i] + kt + 32, lA[i] + nb * 16384);
      gload16(gB + kt + 32, lB + nb * 8192);
      asm volatile("s_waitcnt vmcnt(3) lgkmcnt(0)" ::: "memory");
    } else {
      asm volatile("s_waitcnt vmcnt(0) lgkmcnt(0)" ::: "memory");
    }
    __builtin_amdgcn_sched_barrier(0);
    __builtin_amdgcn_s_barrier();

    bf16x8 bv[4];
    #pragma unroll
    for (int nf = 0; nf < 4; nf++) {
      const int br = wc + nf * 16 + fr;
      bv[nf] = *(const bf16x8*)&Bs[cur][br][(fq ^ ((br >> 1) & 3)) * 8];
    }
    #pragma unroll
    for (int mf = 0; mf < 4; mf++) {
      const int ar = wr + mf * 16 + fr;
      bf16x8 av = *(const bf16x8*)&As[cur][ar][(fq ^ ((ar >> 1) & 3)) * 8];
      #pragma unroll
      for (int nf = 0; nf < 4; nf++)
        acc[mf][nf] = __builtin_amdgcn_mfma_f32_16x16x32_bf16(av, bv[nf], acc[mf][nf], 0, 0, 0);
    }
    __builtin_amdgcn_s_barrier();
    cur = nb;
  }

  int mcol[4];
  #pragma unroll
  for (int nf = 0; nf < 4; nf++)
    mcol[nf] = mask[bz * 1024 + n0 + wc + nf * 16 + fr];

  unsigned short* Pb = P + ((size_t)bz << 20);
  const int slot = ntile * 2 + (wave & 1);        // 0..15, one writer/(slot,row)
  #pragma unroll
  for (int mf = 0; mf < 4; mf++) {
    #pragma unroll
    for (int rr = 0; rr < 4; rr++) {
      const int m = m0 + wr + mf * 16 + fq * 4 + rr;
      float e = 0.f;
      #pragma unroll
      for (int nf = 0; nf < 4; nf++) {
        const float ev = __expf(acc[mf][nf][rr] * SCALE_F);
        e += ev;
        Pb[(size_t)m * 1024 + n0 + wc + nf * 16 + fr] =
            mcol[nf] ? f2bf(ev) : (unsigned short)0;
      }
      e += __shfl_xor(e, 1); e += __shfl_xor(e, 2);
      e += __shfl_xor(e, 4); e += __shfl_xor(e, 8);
      if (fr == 0)
        partial[(size_t)slot * 16384 + bz * 1024 + m] = e;
    }
  }
}

// ---------------------------------------------------------------------------
// pv_attn: XCD-swizzled bf16 GEMM out = inv*(P''·vt^T) - 1e9*mvsum, with the
// final attn write fused into the K-loop. (R16 verbatim — proven)
// ---------------------------------------------------------------------------
__global__ __launch_bounds__(512) void pv_attn(
    const unsigned short* __restrict__ P, const unsigned short* __restrict__ vt,
    const float* __restrict__ partial, const float* __restrict__ mvsum,
    const int* __restrict__ mask,
    float* __restrict__ out, float* __restrict__ attn)
{
  __shared__ __align__(16) unsigned short As[2][64][32];   // 8 KB
  __shared__ __align__(16) unsigned short Bs[2][512][32];  // 64 KB
  __shared__ float inv_l[64];

  const int tid = threadIdx.x;
  const int lin = blockIdx.x;
  const int xcd = lin & 7, idx = lin >> 3;
  const int bz = xcd * 2 + (idx >> 4);
  const int m0 = (idx & 15) * 64;
  const int lane = tid & 63, wave = tid >> 6;
  const int n0 = wave * 64;
  const int fr = lane & 15, fq = lane >> 4;

  f32x4 acc[4][4] = {};

  if (tid < 64) {
    float s = 0.f;
    #pragma unroll
    for (int p = 0; p < 16; p++) s += partial[(size_t)p * 16384 + bz * 1024 + m0 + tid];
    inv_l[tid] = 1.0f / s;
  }

  const unsigned short* gA = nullptr; char* lA = nullptr;
  if (tid < 256) {
    const int row = tid >> 2, slot = tid & 3;
    gA = P + ((size_t)bz << 20) + (size_t)(m0 + row) * 1024 + (slot ^ ((row >> 1) & 3)) * 8;
    lA = (char*)&As[0][0][0] + tid * 16;
  }
  const unsigned short* gB[4]; char* lB[4];
  #pragma unroll
  for (int i = 0; i < 4; i++) {
    const int c = tid + 512 * i, row = c >> 2, slot = c & 3;
    gB[i] = vt + ((size_t)bz * 512 + row) * 1024 + (slot ^ ((row >> 1) & 3)) * 8;
    lB[i] = (char*)&Bs[0][0][0] + c * 16;
  }

  const int arow = tid >> 3, acol = (tid & 7) * 4;
  const int aslot8 = ((acol >> 3) ^ ((arow >> 1) & 3)) * 8 + (acol & 7);
  float* arp = attn + ((size_t)bz * 1024 + m0 + arow) * 1024 + acol;
  const int* mrp = mask + bz * 1024 + acol;

  if (tid < 256) gload16(gA, lA);
  #pragma unroll
  for (int i = 0; i < 4; i++) gload16(gB[i], lB[i]);
  __syncthreads();

  int cur = 0;
  for (int t = 0; t < 32; t++) {
    const int nb = cur ^ 1;
    const int kt = t * 32;
    if (t < 31) {
      if (tid < 256) gload16(gA + kt + 32, lA + nb * 4096);
      #pragma unroll
      for (int i = 0; i < 4; i++) gload16(gB[i] + kt + 32, lB[i] + nb * 32768);
      if (wave < 4) asm volatile("s_waitcnt vmcnt(5) lgkmcnt(0)" ::: "memory");
      else          asm volatile("s_waitcnt vmcnt(4) lgkmcnt(0)" ::: "memory");
    } else {
      asm volatile("s_waitcnt vmcnt(0) lgkmcnt(0)" ::: "memory");
    }
    __builtin_amdgcn_sched_barrier(0);
    __builtin_amdgcn_s_barrier();

    bf16x8 af[4], bv[4];
    #pragma unroll
    for (int mf = 0; mf < 4; mf++) {
      const int ar = mf * 16 + fr;
      af[mf] = *(const bf16x8*)&As[cur][ar][(fq ^ ((ar >> 1) & 3)) * 8];
    }
    #pragma unroll
    for (int nf = 0; nf < 4; nf++) {
      const int br = n0 + nf * 16 + fr;
      bv[nf] = *(const bf16x8*)&Bs[cur][br][(fq ^ ((br >> 1) & 3)) * 8];
    }
    #pragma unroll
    for (int mf = 0; mf < 4; mf++)
      #pragma unroll
      for (int nf = 0; nf < 4; nf++)
        acc[mf][nf] = __builtin_amdgcn_mfma_f32_16x16x32_bf16(af[mf], bv[nf], acc[mf][nf], 0, 0, 0);

    {
      const u16x4 pv4 = *(const u16x4*)&As[cur][arow][aslot8];
      const i32x4 mv = *(const i32x4*)(mrp + kt);
      const float iv = inv_l[arow];
      f32x4 o;
      o[0] = mv[0] ? bf2f(pv4[0]) * iv : NEG_BIG_F;
      o[1] = mv[1] ? bf2f(pv4[1]) * iv : NEG_BIG_F;
      o[2] = mv[2] ? bf2f(pv4[2]) * iv : NEG_BIG_F;
      o[3] = mv[3] ? bf2f(pv4[3]) * iv : NEG_BIG_F;
      *(f32x4*)(arp + kt) = o;
    }
    __builtin_amdgcn_s_barrier();
    cur = nb;
  }

  float mvv[4];
  #pragma unroll
  for (int nf = 0; nf < 4; nf++)
    mvv[nf] = mvsum[bz * 512 + n0 + nf * 16 + fr];
  #pragma unroll
  for (int mf = 0; mf < 4; mf++)
    #pragma unroll
    for (int rr = 0; rr < 4; rr++) {
      const int m = m0 + mf * 16 + fq * 4 + rr;
      const float iv = inv_l[mf * 16 + fq * 4 + rr];
      #pragma unroll
      for (int nf = 0; nf < 4; nf++)
        out[((size_t)bz * 1024 + m) * 512 + n0 + nf * 16 + fr] =
            iv * acc[mf][nf][rr] + NEG_BIG_F * mvv[nf];
    }
}

// ---------------------------------------------------------------------------
extern "C" void kernel_launch(void* const* d_in, const int* in_sizes, int n_in,
                              void* d_out, int out_size, void* d_ws, size_t ws_size,
                              hipStream_t stream)
{
  const float* Q  = (const float*)d_in[0];
  const float* Kx = (const float*)d_in[1];
  const float* V  = (const float*)d_in[2];
  const float* WQ = (const float*)d_in[3];
  const float* WK = (const float*)d_in[4];
  const float* WV = (const float*)d_in[5];
  const int* mask = (const int*)d_in[6];

  const int B = 16, S = 1024, D = 512;
  float* out_f  = (float*)d_out;                      // B*S*D fp32 (final out)
  float* attn_f = out_f + (size_t)B * S * D;          // B*S*S fp32 (final attn)
  unsigned short* Pbuf = (unsigned short*)d_out;      // P'' aliases out region
  unsigned short* xb = (unsigned short*)attn_f;       // bf16 Q|K in attn region

  // ws: qb | kb | vt (8.39M ushorts each) | wb (0.79M) | partial | mvsum
  unsigned short* qb = (unsigned short*)d_ws;
  unsigned short* kb = qb + (size_t)B * S * D;
  unsigned short* vt = kb + (size_t)B * S * D;
  unsigned short* wb = vt + (size_t)B * S * D;
  float* partial = (float*)(wb + 786432);             // 16 x 16384 f32
  float* mvsum = partial + 262144;                    // 16 x 512 f32

  cvtWX<<<dim3(4096, 1, 3), 256, 0, stream>>>(WQ, WK, WV, Q, Kx, wb, xb);
  proj_all<<<dim3(512), 512, 0, stream>>>(xb, V, wb, qb, kb, vt);
  score_mv<<<dim3(1536), 512, 0, stream>>>(qb, kb, vt, mask, Pbuf, partial, mvsum);
  pv_attn<<<dim3(256), 512, 0, stream>>>(Pbuf, vt, partial, mvsum, mask, out_f, attn_f);
}